// Round 1
// baseline (678.238 us; speedup 1.0000x reference)
//
#include <hip/hip_runtime.h>

// ---------------------------------------------------------------------------
// MultiHeadAttention WITHOUT softmax  =>  out[b] = query[b] @ (Wq G[b]) + (bq G[b] + bo)
// where G[b] = (1/8) * blockdiag_h(K_h^T V_h) @ Wo,  K = key@Wk+bk, V = value@Wv+bv
// B=4, S=2048, D=H=1024, heads=16, head_dim=64
// ---------------------------------------------------------------------------

typedef __attribute__((ext_vector_type(8))) short short8;
typedef __attribute__((ext_vector_type(8))) unsigned short ushort8;
typedef __attribute__((ext_vector_type(4))) float f32x4;

__device__ __forceinline__ unsigned short f2bf(float x) {
  unsigned u = __builtin_bit_cast(unsigned, x);
  u += 0x7fffu + ((u >> 16) & 1u);           // RNE
  return (unsigned short)(u >> 16);
}
__device__ __forceinline__ float bf2f(unsigned short b) {
  unsigned u = ((unsigned)b) << 16;
  return __builtin_bit_cast(float, u);
}

__device__ __forceinline__ void split8(const float* __restrict__ p,
                                       ushort8& hi, ushort8& lo) {
  float4 a = *(const float4*)p;
  float4 b = *(const float4*)(p + 4);
  float v[8] = {a.x, a.y, a.z, a.w, b.x, b.y, b.z, b.w};
#pragma unroll
  for (int j = 0; j < 8; ++j) {
    unsigned short h = f2bf(v[j]);
    hi[j] = h;
    lo[j] = f2bf(v[j] - bf2f(h));
  }
}

// C[M x 1024] = A[M x 1024] @ BT[1024 x 1024]^T (+ bias), split-bf16, fp32 I/O.
// 128x128 tile, BK=32, 256 threads = 4 waves (2x2), each wave 64x64 = 4x4 MFMA frags.
__global__ __launch_bounds__(256) void gemm_bt_split(
    const float* __restrict__ A, long long sA,
    const float* __restrict__ BT, long long sB,
    const float* __restrict__ bias, long long sBias,
    float* __restrict__ C, long long sC) {
  // k-slot-major LDS: [kslot(8k)][row][8] -> 16B contiguous per fragment
  __shared__ __align__(16) unsigned short sAhi[4][128][8];
  __shared__ __align__(16) unsigned short sAlo[4][128][8];
  __shared__ __align__(16) unsigned short sBhi[4][128][8];
  __shared__ __align__(16) unsigned short sBlo[4][128][8];

  const int tid = threadIdx.x;
  const int bz = blockIdx.z;
  const float* Ab = A + (size_t)bz * sA;
  const float* Bb = BT + (size_t)bz * sB;
  float* Cb = C + (size_t)bz * sC;
  const size_t m0 = (size_t)blockIdx.x * 128, n0 = (size_t)blockIdx.y * 128;

  f32x4 acc[4][4];
#pragma unroll
  for (int m = 0; m < 4; ++m)
#pragma unroll
    for (int n = 0; n < 4; ++n) acc[m][n] = f32x4{0.f, 0.f, 0.f, 0.f};

  const int wave = tid >> 6, lane = tid & 63;
  const int wr = (wave >> 1) * 64, wc = (wave & 1) * 64;
  const int lr = lane & 15, ksl = lane >> 4;
  const int srow = tid >> 2, sko = tid & 3;

  for (int kt = 0; kt < 32; ++kt) {
    const int k0 = kt * 32;
    __syncthreads();
#pragma unroll
    for (int t = 0; t < 2; ++t) {
      const int row = srow + t * 64;
      ushort8 hi, lo;
      split8(Ab + (m0 + row) * 1024 + k0 + sko * 8, hi, lo);
      *(ushort8*)&sAhi[sko][row][0] = hi;
      *(ushort8*)&sAlo[sko][row][0] = lo;
      split8(Bb + (n0 + row) * 1024 + k0 + sko * 8, hi, lo);
      *(ushort8*)&sBhi[sko][row][0] = hi;
      *(ushort8*)&sBlo[sko][row][0] = lo;
    }
    __syncthreads();

    short8 ah[4], al[4], bh[4], bl[4];
#pragma unroll
    for (int m = 0; m < 4; ++m) {
      ah[m] = *(const short8*)&sAhi[ksl][wr + m * 16 + lr][0];
      al[m] = *(const short8*)&sAlo[ksl][wr + m * 16 + lr][0];
    }
#pragma unroll
    for (int n = 0; n < 4; ++n) {
      bh[n] = *(const short8*)&sBhi[ksl][wc + n * 16 + lr][0];
      bl[n] = *(const short8*)&sBlo[ksl][wc + n * 16 + lr][0];
    }
#pragma unroll
    for (int m = 0; m < 4; ++m)
#pragma unroll
      for (int n = 0; n < 4; ++n) {
        acc[m][n] = __builtin_amdgcn_mfma_f32_16x16x32_bf16(ah[m], bh[n], acc[m][n], 0, 0, 0);
        acc[m][n] = __builtin_amdgcn_mfma_f32_16x16x32_bf16(ah[m], bl[n], acc[m][n], 0, 0, 0);
        acc[m][n] = __builtin_amdgcn_mfma_f32_16x16x32_bf16(al[m], bh[n], acc[m][n], 0, 0, 0);
      }
  }

  // C/D layout (m89-verified): col = lane&15, row = (lane>>4)*4 + r
#pragma unroll
  for (int n = 0; n < 4; ++n) {
    const size_t col = n0 + wc + n * 16 + lr;
    const float bval = bias ? bias[(size_t)bz * sBias + col] : 0.0f;
#pragma unroll
    for (int m = 0; m < 4; ++m) {
      const size_t rb = m0 + wr + m * 16 + ksl * 4;
#pragma unroll
      for (int r = 0; r < 4; ++r)
        Cb[(rb + r) * 1024 + col] = acc[m][n][r] + bval;
    }
  }
}

// dst[i][d] = src[d][i], 1024x1024
__global__ __launch_bounds__(256) void transpose1024(const float* __restrict__ src,
                                                     float* __restrict__ dst) {
  __shared__ float t[32][33];
  const int bx = blockIdx.x * 32, by = blockIdx.y * 32;
  const int tx = threadIdx.x & 31, ty = threadIdx.x >> 5;  // ty 0..7
#pragma unroll
  for (int i = 0; i < 32; i += 8)
    t[ty + i][tx] = src[(size_t)(by + ty + i) * 1024 + bx + tx];
  __syncthreads();
#pragma unroll
  for (int i = 0; i < 32; i += 8)
    dst[(size_t)(bx + ty + i) * 1024 + by + tx] = t[tx][ty + i];
}

// Mpart[chunk][bh][r][c] = sum_{s in chunk} K[b,s,h*64+r] * V[b,s,h*64+c]   (fp32 exact)
__global__ __launch_bounds__(256) void ktv_partial(const float* __restrict__ Kbuf,
                                                   const float* __restrict__ Vbuf,
                                                   float* __restrict__ Mpart) {
  const int chunk = blockIdx.x;  // 0..7  (256 s each)
  const int bh = blockIdx.y;     // 0..63
  const int b = bh >> 4, h = bh & 15;
  __shared__ float Ks[64][64];
  __shared__ float Vs[64][64];
  const int tid = threadIdx.x;
  const int r0 = tid >> 4;         // 0..15
  const int c0 = (tid & 15) * 4;   // 0..60
  float acc[4][4] = {};
  const size_t base = ((size_t)(b * 2048 + chunk * 256)) * 1024 + h * 64;
  const float* Kb = Kbuf + base;
  const float* Vb = Vbuf + base;
  for (int slab = 0; slab < 4; ++slab) {
    __syncthreads();
#pragma unroll
    for (int t = 0; t < 4; ++t) {
      const int task = tid + t * 256;  // 0..1023
      const int si = task >> 4, c4 = (task & 15) * 4;
      const size_t off = (size_t)(slab * 64 + si) * 1024 + c4;
      *(float4*)&Ks[si][c4] = *(const float4*)(Kb + off);
      *(float4*)&Vs[si][c4] = *(const float4*)(Vb + off);
    }
    __syncthreads();
    for (int s = 0; s < 64; ++s) {
      float4 v = *(float4*)&Vs[s][c0];
#pragma unroll
      for (int i = 0; i < 4; ++i) {
        const float kk = Ks[s][r0 + 16 * i];
        acc[i][0] += kk * v.x; acc[i][1] += kk * v.y;
        acc[i][2] += kk * v.z; acc[i][3] += kk * v.w;
      }
    }
  }
  float* outp = Mpart + ((size_t)chunk * 64 + bh) * 4096;
#pragma unroll
  for (int i = 0; i < 4; ++i)
    *(float4*)&outp[(r0 + 16 * i) * 64 + c0] = *(float4*)&acc[i][0];
}

__global__ __launch_bounds__(256) void ktv_reduce(const float* __restrict__ Mpart,
                                                  float* __restrict__ M) {
  const size_t idx = (size_t)blockIdx.x * 256 + threadIdx.x;  // 262144 total
  float s = 0.f;
#pragma unroll
  for (int c = 0; c < 8; ++c) s += Mpart[(size_t)c * 262144 + idx];
  M[idx] = s;
}

// GT[b][j][h*64+r] = (1/8) * sum_c M[b,h][r][c] * Wo[h*64+c][j]
__global__ __launch_bounds__(256) void build_gt(const float* __restrict__ M,
                                                const float* __restrict__ Wo,
                                                float* __restrict__ GT) {
  const int bh = blockIdx.x;
  const int b = bh >> 4, h = bh & 15;
  __shared__ float Ms[64][65];
  __shared__ float Wos[64][65];
  const int tid = threadIdx.x;
  for (int t = tid; t < 4096; t += 256) Ms[t >> 6][t & 63] = M[(size_t)bh * 4096 + t];
  const int r = tid & 63, jg = tid >> 6;
  for (int jt = 0; jt < 16; ++jt) {
    __syncthreads();
    for (int t = tid; t < 4096; t += 256) {
      const int c = t >> 6, jj = t & 63;
      Wos[c][jj] = Wo[(size_t)(h * 64 + c) * 1024 + jt * 64 + jj];
    }
    __syncthreads();
#pragma unroll
    for (int ji = 0; ji < 16; ++ji) {
      const int j = jg + ji * 4;
      float s = 0.f;
#pragma unroll
      for (int c = 0; c < 64; ++c) s += Ms[r][c] * Wos[c][j];
      GT[(size_t)b * 1048576 + (size_t)(jt * 64 + j) * 1024 + h * 64 + r] = 0.125f * s;
    }
  }
}

// cv[b][j] = bo[j] + sum_i bq[i] * GT[b][j][i]
__global__ __launch_bounds__(256) void cvec_kernel(const float* __restrict__ GT,
                                                   const float* __restrict__ bq,
                                                   const float* __restrict__ bo,
                                                   float* __restrict__ cv) {
  const int row = blockIdx.x * 4 + (threadIdx.x >> 6);  // 0..4095
  const int lane = threadIdx.x & 63;
  const int b = row >> 10, j = row & 1023;
  const float* g = GT + (size_t)b * 1048576 + (size_t)j * 1024;
  float s = 0.f;
#pragma unroll
  for (int i = lane * 4; i < 1024; i += 256) {
    float4 v = *(const float4*)&g[i];
    float4 q = *(const float4*)&bq[i];
    s += v.x * q.x + v.y * q.y + v.z * q.z + v.w * q.w;
  }
#pragma unroll
  for (int o = 32; o; o >>= 1) s += __shfl_down(s, o);
  if (lane == 0) cv[row] = s + bo[j];
}

extern "C" void kernel_launch(void* const* d_in, const int* in_sizes, int n_in,
                              void* d_out, int out_size, void* d_ws, size_t ws_size,
                              hipStream_t stream) {
  const float* query = (const float*)d_in[0];
  const float* key   = (const float*)d_in[1];
  const float* value = (const float*)d_in[2];
  const float* Wq = (const float*)d_in[3];
  const float* bq = (const float*)d_in[4];
  const float* Wk = (const float*)d_in[5];
  const float* bk = (const float*)d_in[6];
  const float* Wv = (const float*)d_in[7];
  const float* bv = (const float*)d_in[8];
  const float* Wo = (const float*)d_in[9];
  const float* bo = (const float*)d_in[10];
  float* out = (float*)d_out;
  float* ws = (float*)d_ws;

  // workspace layout (floats); regions reused once producers are dead.
  float* Kbuf  = ws;              // 8,388,608  (32 MB)
  float* Vbuf  = ws + 8388608;    // 8,388,608
  float* WkT   = ws + 16777216;   // 1,048,576
  float* WvT   = ws + 17825792;   // 1,048,576
  float* Mpart = ws + 18874368;   // 2,097,152
  float* Msum  = ws + 20971520;   //   262,144   -> peak ~85 MB
  float* GT    = ws;              // 4,194,304  (reuse: Kbuf dead)
  float* FT    = ws + 4194304;    // 4,194,304  (reuse: Kbuf dead)
  float* cv    = ws + 16777216;   //     4,096  (reuse: WkT dead)

  transpose1024<<<dim3(32, 32), 256, 0, stream>>>(Wk, WkT);
  transpose1024<<<dim3(32, 32), 256, 0, stream>>>(Wv, WvT);

  // K = key@Wk + bk ; V = value@Wv + bv    (8192 x 1024)
  gemm_bt_split<<<dim3(64, 8, 1), 256, 0, stream>>>(key, 0, WkT, 0, bk, 0, Kbuf, 0);
  gemm_bt_split<<<dim3(64, 8, 1), 256, 0, stream>>>(value, 0, WvT, 0, bv, 0, Vbuf, 0);

  // M[b,h] = K_h^T V_h  (fp32 exact)
  ktv_partial<<<dim3(8, 64), 256, 0, stream>>>(Kbuf, Vbuf, Mpart);
  ktv_reduce<<<1024, 256, 0, stream>>>(Mpart, Msum);

  // GT[b] = G[b]^T ; cv[b] = bq@G[b] + bo
  build_gt<<<64, 256, 0, stream>>>(Msum, Wo, GT);
  cvec_kernel<<<1024, 256, 0, stream>>>(GT, bq, bo, cv);

  // FT[b] = (Wq @ G[b])^T = GT[b] @ Wq^T   => gemm_bt(A=GT[b], BT=Wq)
  gemm_bt_split<<<dim3(8, 8, 4), 256, 0, stream>>>(GT, 1048576, Wq, 0,
                                                   (const float*)nullptr, 0, FT, 1048576);

  // out[b] = query[b] @ FT[b]^T + cv[b]
  gemm_bt_split<<<dim3(16, 8, 4), 256, 0, stream>>>(query, 2097152, FT, 1048576,
                                                    cv, 1024, out, 2097152);
}

// Round 2
// 345.204 us; speedup vs baseline: 1.9647x; 1.9647x over previous
//
#include <hip/hip_runtime.h>

// ---------------------------------------------------------------------------
// MultiHeadAttention WITHOUT softmax:
//   out[b] = query[b] @ F[b] + cv[b]
//   F[b]   = 0.125 * (Wq . blockdiag_h(M[b,h])) @ Wo = 0.125 * WqM[b] @ Wo
//   M[b,h] = K_h^T V_h,  K = key@Wk+bk, V = value@Wv+bv
//   cv[b]  = bo + 0.125 * (bq . blockdiag(M[b])) @ Wo
// B=4, S=2048, D=H=1024, heads=16, head_dim=64
// ---------------------------------------------------------------------------

typedef __attribute__((ext_vector_type(8))) short short8;
typedef __attribute__((ext_vector_type(8))) unsigned short ushort8;
typedef __attribute__((ext_vector_type(4))) float f32x4;

__device__ __forceinline__ unsigned short f2bf(float x) {
  unsigned u = __builtin_bit_cast(unsigned, x);
  u += 0x7fffu + ((u >> 16) & 1u);           // RNE
  return (unsigned short)(u >> 16);
}
__device__ __forceinline__ float bf2f(unsigned short b) {
  unsigned u = ((unsigned)b) << 16;
  return __builtin_bit_cast(float, u);
}

__device__ __forceinline__ void split8(const float* __restrict__ p,
                                       ushort8& hi, ushort8& lo) {
  float4 a = *(const float4*)p;
  float4 b = *(const float4*)(p + 4);
  float v[8] = {a.x, a.y, a.z, a.w, b.x, b.y, b.z, b.w};
#pragma unroll
  for (int j = 0; j < 8; ++j) {
    unsigned short h = f2bf(v[j]);
    hi[j] = h;
    lo[j] = f2bf(v[j] - bf2f(h));
  }
}

// C[M x 1024] = A[M x 1024] @ BT[1024 x 1024]^T (+ bias), split-bf16, fp32 I/O.
// 128x128 tile, BK=32, 256 threads = 4 waves (2x2), each wave 64x64 = 4x4 MFMA frags.
__global__ __launch_bounds__(256) void gemm_bt_split(
    const float* __restrict__ A, long long sA,
    const float* __restrict__ BT, long long sB,
    const float* __restrict__ bias, long long sBias,
    float* __restrict__ C, long long sC) {
  // k-slot-major LDS: [kslot(8k)][row][8] -> 16B contiguous per fragment
  __shared__ __align__(16) unsigned short sAhi[4][128][8];
  __shared__ __align__(16) unsigned short sAlo[4][128][8];
  __shared__ __align__(16) unsigned short sBhi[4][128][8];
  __shared__ __align__(16) unsigned short sBlo[4][128][8];

  const int tid = threadIdx.x;
  const int bz = blockIdx.z;
  const float* Ab = A + (size_t)bz * sA;
  const float* Bb = BT + (size_t)bz * sB;
  float* Cb = C + (size_t)bz * sC;
  const size_t m0 = (size_t)blockIdx.x * 128, n0 = (size_t)blockIdx.y * 128;

  f32x4 acc[4][4];
#pragma unroll
  for (int m = 0; m < 4; ++m)
#pragma unroll
    for (int n = 0; n < 4; ++n) acc[m][n] = f32x4{0.f, 0.f, 0.f, 0.f};

  const int wave = tid >> 6, lane = tid & 63;
  const int wr = (wave >> 1) * 64, wc = (wave & 1) * 64;
  const int lr = lane & 15, ksl = lane >> 4;
  const int srow = tid >> 2, sko = tid & 3;

  for (int kt = 0; kt < 32; ++kt) {
    const int k0 = kt * 32;
    __syncthreads();
#pragma unroll
    for (int t = 0; t < 2; ++t) {
      const int row = srow + t * 64;
      ushort8 hi, lo;
      split8(Ab + (m0 + row) * 1024 + k0 + sko * 8, hi, lo);
      *(ushort8*)&sAhi[sko][row][0] = hi;
      *(ushort8*)&sAlo[sko][row][0] = lo;
      split8(Bb + (n0 + row) * 1024 + k0 + sko * 8, hi, lo);
      *(ushort8*)&sBhi[sko][row][0] = hi;
      *(ushort8*)&sBlo[sko][row][0] = lo;
    }
    __syncthreads();

    short8 ah[4], al[4], bh[4], bl[4];
#pragma unroll
    for (int m = 0; m < 4; ++m) {
      ah[m] = *(const short8*)&sAhi[ksl][wr + m * 16 + lr][0];
      al[m] = *(const short8*)&sAlo[ksl][wr + m * 16 + lr][0];
    }
#pragma unroll
    for (int n = 0; n < 4; ++n) {
      bh[n] = *(const short8*)&sBhi[ksl][wc + n * 16 + lr][0];
      bl[n] = *(const short8*)&sBlo[ksl][wc + n * 16 + lr][0];
    }
#pragma unroll
    for (int m = 0; m < 4; ++m)
#pragma unroll
      for (int n = 0; n < 4; ++n) {
        acc[m][n] = __builtin_amdgcn_mfma_f32_16x16x32_bf16(ah[m], bh[n], acc[m][n], 0, 0, 0);
        acc[m][n] = __builtin_amdgcn_mfma_f32_16x16x32_bf16(ah[m], bl[n], acc[m][n], 0, 0, 0);
        acc[m][n] = __builtin_amdgcn_mfma_f32_16x16x32_bf16(al[m], bh[n], acc[m][n], 0, 0, 0);
      }
  }

  // C/D layout (m89-verified): col = lane&15, row = (lane>>4)*4 + r
#pragma unroll
  for (int n = 0; n < 4; ++n) {
    const size_t col = n0 + wc + n * 16 + lr;
    const float bval = bias ? bias[(size_t)bz * sBias + col] : 0.0f;
#pragma unroll
    for (int m = 0; m < 4; ++m) {
      const size_t rb = m0 + wr + m * 16 + ksl * 4;
#pragma unroll
      for (int r = 0; r < 4; ++r)
        Cb[(rb + r) * 1024 + col] = acc[m][n][r] + bval;
    }
  }
}

// dst[i][d] = src[d][i], 1024x1024
__global__ __launch_bounds__(256) void transpose1024(const float* __restrict__ src,
                                                     float* __restrict__ dst) {
  __shared__ float t[32][33];
  const int bx = blockIdx.x * 32, by = blockIdx.y * 32;
  const int tx = threadIdx.x & 31, ty = threadIdx.x >> 5;  // ty 0..7
#pragma unroll
  for (int i = 0; i < 32; i += 8)
    t[ty + i][tx] = src[(size_t)(by + ty + i) * 1024 + bx + tx];
  __syncthreads();
#pragma unroll
  for (int i = 0; i < 32; i += 8)
    dst[(size_t)(bx + ty + i) * 1024 + by + tx] = t[tx][ty + i];
}

// Mpart[chunk][bh][r][c] = sum_{s in chunk} K[b,s,h*64+r] * V[b,s,h*64+c]   (fp32 exact)
__global__ __launch_bounds__(256) void ktv_partial(const float* __restrict__ Kbuf,
                                                   const float* __restrict__ Vbuf,
                                                   float* __restrict__ Mpart) {
  const int chunk = blockIdx.x;  // 0..7  (256 s each)
  const int bh = blockIdx.y;     // 0..63
  const int b = bh >> 4, h = bh & 15;
  __shared__ float Ks[64][64];
  __shared__ float Vs[64][64];
  const int tid = threadIdx.x;
  const int r0 = tid >> 4;         // 0..15
  const int c0 = (tid & 15) * 4;   // 0..60
  float acc[4][4] = {};
  const size_t base = ((size_t)(b * 2048 + chunk * 256)) * 1024 + h * 64;
  const float* Kb = Kbuf + base;
  const float* Vb = Vbuf + base;
  for (int slab = 0; slab < 4; ++slab) {
    __syncthreads();
#pragma unroll
    for (int t = 0; t < 4; ++t) {
      const int task = tid + t * 256;  // 0..1023
      const int si = task >> 4, c4 = (task & 15) * 4;
      const size_t off = (size_t)(slab * 64 + si) * 1024 + c4;
      *(float4*)&Ks[si][c4] = *(const float4*)(Kb + off);
      *(float4*)&Vs[si][c4] = *(const float4*)(Vb + off);
    }
    __syncthreads();
    for (int s = 0; s < 64; ++s) {
      float4 v = *(float4*)&Vs[s][c0];
#pragma unroll
      for (int i = 0; i < 4; ++i) {
        const float kk = Ks[s][r0 + 16 * i];
        acc[i][0] += kk * v.x; acc[i][1] += kk * v.y;
        acc[i][2] += kk * v.z; acc[i][3] += kk * v.w;
      }
    }
  }
  float* outp = Mpart + ((size_t)chunk * 64 + bh) * 4096;
#pragma unroll
  for (int i = 0; i < 4; ++i)
    *(float4*)&outp[(r0 + 16 * i) * 64 + c0] = *(float4*)&acc[i][0];
}

__global__ __launch_bounds__(256) void ktv_reduce(const float* __restrict__ Mpart,
                                                  float* __restrict__ M) {
  const size_t idx = (size_t)blockIdx.x * 256 + threadIdx.x;  // 262144 total
  float s = 0.f;
#pragma unroll
  for (int c = 0; c < 8; ++c) s += Mpart[(size_t)c * 262144 + idx];
  M[idx] = s;
}

// WqM[b][d][h*64+c] = 0.125 * sum_r Wq[d][h*64+r] * M[b,h][r][c]
// grid (dseg=8, h=16, b=4), 256 threads; block covers 128 d-rows x 64 c.
__global__ __launch_bounds__(256) void wqm_kernel(const float* __restrict__ M,
                                                  const float* __restrict__ Wq,
                                                  float* __restrict__ WqM) {
  const int dseg = blockIdx.x, h = blockIdx.y, b = blockIdx.z;
  __shared__ __align__(16) float WqS[128][68];
  __shared__ __align__(16) float Ms[64][68];
  const int t = threadIdx.x;
#pragma unroll
  for (int it = 0; it < 8; ++it) {
    const int task = t + it * 256;
    const int row = task >> 4, c4 = (task & 15) * 4;
    *(float4*)&WqS[row][c4] =
        *(const float4*)&Wq[(size_t)(dseg * 128 + row) * 1024 + h * 64 + c4];
  }
#pragma unroll
  for (int it = 0; it < 4; ++it) {
    const int task = t + it * 256;
    const int row = task >> 4, c4 = (task & 15) * 4;
    *(float4*)&Ms[row][c4] =
        *(const float4*)&M[((size_t)(b * 16 + h)) * 4096 + row * 64 + c4];
  }
  __syncthreads();

  const int c0 = (t & 7) * 8;   // 8 columns per thread
  const int d0 = t >> 3;        // 0..31; rows d0 + 32*i
  float4 a0[4], a1[4];
#pragma unroll
  for (int i = 0; i < 4; ++i) {
    a0[i] = float4{0.f, 0.f, 0.f, 0.f};
    a1[i] = float4{0.f, 0.f, 0.f, 0.f};
  }
  for (int r = 0; r < 64; ++r) {
    const float4 m0 = *(const float4*)&Ms[r][c0];
    const float4 m1 = *(const float4*)&Ms[r][c0 + 4];
#pragma unroll
    for (int i = 0; i < 4; ++i) {
      const float w = WqS[d0 + 32 * i][r];
      a0[i].x += w * m0.x; a0[i].y += w * m0.y; a0[i].z += w * m0.z; a0[i].w += w * m0.w;
      a1[i].x += w * m1.x; a1[i].y += w * m1.y; a1[i].z += w * m1.z; a1[i].w += w * m1.w;
    }
  }
#pragma unroll
  for (int i = 0; i < 4; ++i) {
    const size_t row = (size_t)(dseg * 128 + d0 + 32 * i);
    float* p = WqM + ((size_t)b << 20) + row * 1024 + h * 64 + c0;
    float4 o0 = a0[i], o1 = a1[i];
    o0.x *= 0.125f; o0.y *= 0.125f; o0.z *= 0.125f; o0.w *= 0.125f;
    o1.x *= 0.125f; o1.y *= 0.125f; o1.z *= 0.125f; o1.w *= 0.125f;
    *(float4*)p = o0;
    *(float4*)(p + 4) = o1;
  }
}

// bqM[b][h*64+c] = sum_r bq[h*64+r] * M[b,h][r][c]
__global__ __launch_bounds__(256) void bqm_kernel(const float* __restrict__ M,
                                                  const float* __restrict__ bq,
                                                  float* __restrict__ bqM) {
  const int h = blockIdx.x, b = blockIdx.y;
  __shared__ float part[4][64];
  const int t = threadIdx.x;
  const int c = t & 63, rq = t >> 6;
  const float* Mb = M + ((size_t)(b * 16 + h)) * 4096;
  float s = 0.f;
#pragma unroll
  for (int ri = 0; ri < 16; ++ri) {
    const int r = rq * 16 + ri;
    s += bq[h * 64 + r] * Mb[r * 64 + c];
  }
  part[rq][c] = s;
  __syncthreads();
  if (t < 64) {
    bqM[(size_t)b * 1024 + h * 64 + t] =
        part[0][t] + part[1][t] + part[2][t] + part[3][t];
  }
}

// cv[b][j] = bo[j] + 0.125 * sum_k bqM[b][k] * Wo[k][j]
__global__ __launch_bounds__(256) void cv_kernel(const float* __restrict__ bqM,
                                                 const float* __restrict__ Wo,
                                                 const float* __restrict__ bo,
                                                 float* __restrict__ cv) {
  const int j = blockIdx.x * 256 + threadIdx.x;
  const int b = blockIdx.y;
  const float* q = bqM + (size_t)b * 1024;
  float s = 0.f;
  for (int k = 0; k < 1024; ++k)
    s += q[k] * Wo[(size_t)k * 1024 + j];
  cv[(size_t)b * 1024 + j] = s * 0.125f + bo[j];
}

extern "C" void kernel_launch(void* const* d_in, const int* in_sizes, int n_in,
                              void* d_out, int out_size, void* d_ws, size_t ws_size,
                              hipStream_t stream) {
  const float* query = (const float*)d_in[0];
  const float* key   = (const float*)d_in[1];
  const float* value = (const float*)d_in[2];
  const float* Wq = (const float*)d_in[3];
  const float* bq = (const float*)d_in[4];
  const float* Wk = (const float*)d_in[5];
  const float* bk = (const float*)d_in[6];
  const float* Wv = (const float*)d_in[7];
  const float* bv = (const float*)d_in[8];
  const float* Wo = (const float*)d_in[9];
  const float* bo = (const float*)d_in[10];
  float* out = (float*)d_out;
  float* ws = (float*)d_ws;

  // workspace layout (floats); regions reused once producers are dead.
  float* Kbuf  = ws;              // 8,388,608 (dead after ktv_partial)
  float* Vbuf  = ws + 8388608;    // 8,388,608 (dead after ktv_partial)
  float* WkT   = ws + 16777216;   // 1,048,576 (dead after K projection)
  float* WvT   = ws + 17825792;   // 1,048,576 (dead after V projection)
  float* Mpart = ws + 18874368;   // 2,097,152 (dead after ktv_reduce)
  float* Msum  = ws + 20971520;   //   262,144
  float* WqM   = ws;              // 4,194,304 (reuse Kbuf)
  float* FT    = ws + 4194304;    // 4,194,304 (reuse Kbuf tail)
  float* WoT   = ws + 16777216;   // 1,048,576 (reuse WkT)
  float* bqM   = ws + 17825792;   //     4,096 (reuse WvT)
  float* cv    = ws + 18874368;   //     4,096 (reuse Mpart)

  transpose1024<<<dim3(32, 32), 256, 0, stream>>>(Wk, WkT);
  transpose1024<<<dim3(32, 32), 256, 0, stream>>>(Wv, WvT);

  // K = key@Wk + bk ; V = value@Wv + bv    (8192 x 1024)
  gemm_bt_split<<<dim3(64, 8, 1), 256, 0, stream>>>(key, 0, WkT, 0, bk, 0, Kbuf, 0);
  gemm_bt_split<<<dim3(64, 8, 1), 256, 0, stream>>>(value, 0, WvT, 0, bv, 0, Vbuf, 0);

  // M[b,h] = K_h^T V_h  (fp32 exact)
  ktv_partial<<<dim3(8, 64), 256, 0, stream>>>(Kbuf, Vbuf, Mpart);
  ktv_reduce<<<1024, 256, 0, stream>>>(Mpart, Msum);

  // WoT for the F-transpose GEMM (Kbuf/WkT now dead)
  transpose1024<<<dim3(32, 32), 256, 0, stream>>>(Wo, WoT);

  // WqM[b] = 0.125 * Wq . blockdiag(M[b]);  bias fold
  wqm_kernel<<<dim3(8, 16, 4), 256, 0, stream>>>(Msum, Wq, WqM);
  bqm_kernel<<<dim3(16, 4), 256, 0, stream>>>(Msum, bq, bqM);
  cv_kernel<<<dim3(4, 4), 256, 0, stream>>>(bqM, Wo, bo, cv);

  // FT[b] = (WqM[b] @ Wo)^T = gemm_bt(A=WoT, BT=WqM[b])
  gemm_bt_split<<<dim3(8, 8, 4), 256, 0, stream>>>(WoT, 0, WqM, 1048576,
                                                   (const float*)nullptr, 0, FT, 1048576);

  // out[b] = query[b] @ FT[b]^T + cv[b]
  gemm_bt_split<<<dim3(16, 8, 4), 256, 0, stream>>>(query, 2097152, FT, 1048576,
                                                    cv, 1024, out, 2097152);
}

// Round 3
// 336.625 us; speedup vs baseline: 2.0148x; 1.0255x over previous
//
#include <hip/hip_runtime.h>

// ---------------------------------------------------------------------------
// MHA without softmax, fully reassociated:
//   out[b] = query[b] @ F[b] + cv[b]
//   F[b]   = 0.125 * WqM[b] @ Wo,  WqM[b] = Wq . blockdiag_h(M[b,h])
//   M[b,h] = Wk_h^T C[b] Wv_h + (Wk_h^T ksum) bv_h^T + bk_h (vsum^T Wv_h) + S bk_h bv_h^T
//   C[b]   = key[b]^T value[b]   (D := value^T key = C^T)
// B=4, S=2048, D=H=1024, heads=16, head_dim=64
// Split-bf16 (hi+lo, 3 MFMAs) GEMMs over pre-tiled images staged by
// global_load_lds; small contractions in exact fp32.
// ---------------------------------------------------------------------------

typedef __attribute__((ext_vector_type(8))) short short8;
typedef __attribute__((ext_vector_type(8))) unsigned short ushort8;
typedef __attribute__((ext_vector_type(4))) float f32x4;

__device__ __forceinline__ unsigned short f2bf(float x) {
  unsigned u = __builtin_bit_cast(unsigned, x);
  u += 0x7fffu + ((u >> 16) & 1u);  // RNE
  return (unsigned short)(u >> 16);
}
__device__ __forceinline__ float bf2f(unsigned short b) {
  unsigned u = ((unsigned)b) << 16;
  return __builtin_bit_cast(float, u);
}

__device__ __forceinline__ void gload16(const unsigned short* g, unsigned short* l) {
  __builtin_amdgcn_global_load_lds(
      (const __attribute__((address_space(1))) unsigned int*)g,
      (__attribute__((address_space(3))) unsigned int*)l, 16, 0, 0);
}

// ---------------------------------------------------------------------------
// tileimg: build split-bf16 pre-tiled image of logical matrix R[rows][K].
//   transposed==0: R[r][k] = src[r][k]   (src row-major, 1024 cols)
//   transposed==1: R[r][k] = src[k][r]
// Blob per (rowblk, kt): 8192 ushorts = hi[4][128][8] || lo[4][128][8],
//   hi[ksl][r][j] = bf16(R[rb*128+r][kt*32 + ksl*8 + j]), lo = residue.
// grid: (nRowBlk, NKT, B)
// ---------------------------------------------------------------------------
__global__ __launch_bounds__(256) void tileimg(const float* __restrict__ src,
                                               long long sSrcB, int transposed,
                                               unsigned short* __restrict__ img) {
  const int rb = blockIdx.x, kt = blockIdx.y, b = blockIdx.z;
  const int NRB = gridDim.x, NKT = gridDim.y;
  __shared__ __align__(16) float tile[128][36];
  const int t = threadIdx.x;
  const float* s = src + (size_t)b * sSrcB;
  if (!transposed) {
#pragma unroll
    for (int p = 0; p < 4; ++p) {
      const int idx = p * 1024 + t * 4;
      const int r = idx >> 5, k = idx & 31;
      *(float4*)&tile[r][k] =
          *(const float4*)&s[(size_t)(rb * 128 + r) * 1024 + kt * 32 + k];
    }
  } else {
#pragma unroll
    for (int p = 0; p < 4; ++p) {
      const int idx = p * 1024 + t * 4;
      const int k = idx >> 7, r = idx & 127;
      float4 v = *(const float4*)&s[(size_t)(kt * 32 + k) * 1024 + rb * 128 + r];
      tile[r + 0][k] = v.x;
      tile[r + 1][k] = v.y;
      tile[r + 2][k] = v.z;
      tile[r + 3][k] = v.w;
    }
  }
  __syncthreads();
  unsigned short* blob = img + ((size_t)(b * NRB + rb) * NKT + kt) * 8192;
  const int r = t >> 1, kh = (t & 1) * 16;
  ushort8 hi0, lo0, hi1, lo1;
#pragma unroll
  for (int j = 0; j < 8; ++j) {
    float x = tile[r][kh + j];
    unsigned short h = f2bf(x);
    hi0[j] = h;
    lo0[j] = f2bf(x - bf2f(h));
    float y = tile[r][kh + 8 + j];
    unsigned short g = f2bf(y);
    hi1[j] = g;
    lo1[j] = f2bf(y - bf2f(g));
  }
  const int k0sl = kh >> 3;  // 0 or 2
  *(ushort8*)&blob[k0sl * 1024 + r * 8] = hi0;
  *(ushort8*)&blob[(k0sl + 1) * 1024 + r * 8] = hi1;
  *(ushort8*)&blob[4096 + k0sl * 1024 + r * 8] = lo0;
  *(ushort8*)&blob[4096 + (k0sl + 1) * 1024 + r * 8] = lo1;
}

// ---------------------------------------------------------------------------
// gemm_img: C[m][n] (+bias[n]) = sum_k A[m][k]*BT[n][k], split-bf16 3-MFMA.
// 128x128 tile, BK=32, 4 waves; LDS double-buffer staged via global_load_lds;
// one barrier per k-step (next-tile loads in flight during MFMA phase).
// ---------------------------------------------------------------------------
__global__ __launch_bounds__(256) void gemm_img(
    const unsigned short* __restrict__ Aimg, long long sAb,
    const unsigned short* __restrict__ Bimg, long long sBb,
    const float* __restrict__ bias, long long sBiasB, float* __restrict__ C,
    long long sCb, int NKT) {
  __shared__ __align__(16) unsigned short sAB[2][16384];
  const int tid = threadIdx.x, w = tid >> 6, l = tid & 63;

  // XCD-chunk swizzle (all grids have total % 8 == 0)
  const int gx = gridDim.x, gy = gridDim.y;
  int flat = blockIdx.x + gx * (blockIdx.y + gy * blockIdx.z);
  const int total = gx * gy * gridDim.z;
  flat = (flat & 7) * (total >> 3) + (flat >> 3);
  const int bx = flat % gx;
  const int rest = flat / gx;
  const int by = rest % gy, bz = rest / gy;

  const unsigned short* Ab = Aimg + (size_t)bz * sAb + (size_t)bx * NKT * 8192;
  const unsigned short* Bb = Bimg + (size_t)bz * sBb + (size_t)by * NKT * 8192;

  f32x4 acc[4][4];
#pragma unroll
  for (int m = 0; m < 4; ++m)
#pragma unroll
    for (int n = 0; n < 4; ++n) acc[m][n] = f32x4{0.f, 0.f, 0.f, 0.f};

  const int wr = (w >> 1) * 64, wc = (w & 1) * 64, lr = l & 15, ksl = l >> 4;
  const int stg = w * 512 + l * 8;

#define STAGE(KT, BUF)                                                        \
  {                                                                           \
    const unsigned short* As_ = Ab + (size_t)(KT)*8192;                       \
    const unsigned short* Bs_ = Bb + (size_t)(KT)*8192;                       \
    _Pragma("unroll") for (int i = 0; i < 4; ++i)                             \
        gload16(As_ + i * 2048 + stg, &sAB[BUF][i * 2048 + w * 512]);         \
    _Pragma("unroll") for (int i = 0; i < 4; ++i)                             \
        gload16(Bs_ + i * 2048 + stg, &sAB[BUF][8192 + i * 2048 + w * 512]);  \
  }

  STAGE(0, 0);
  for (int kt = 0; kt < NKT; ++kt) {
    __syncthreads();  // drains vmcnt(0): buf kt&1 ready; prev reads done
    if (kt + 1 < NKT) STAGE(kt + 1, (kt + 1) & 1);
    const unsigned short* sb = sAB[kt & 1];
    short8 ah[4], al[4], bh[4], bl[4];
#pragma unroll
    for (int m = 0; m < 4; ++m) {
      const int ro = ksl * 1024 + (wr + m * 16 + lr) * 8;
      ah[m] = *(const short8*)&sb[ro];
      al[m] = *(const short8*)&sb[4096 + ro];
    }
#pragma unroll
    for (int n = 0; n < 4; ++n) {
      const int ro = ksl * 1024 + (wc + n * 16 + lr) * 8;
      bh[n] = *(const short8*)&sb[8192 + ro];
      bl[n] = *(const short8*)&sb[12288 + ro];
    }
#pragma unroll
    for (int m = 0; m < 4; ++m)
#pragma unroll
      for (int n = 0; n < 4; ++n) {
        acc[m][n] = __builtin_amdgcn_mfma_f32_16x16x32_bf16(ah[m], bh[n], acc[m][n], 0, 0, 0);
        acc[m][n] = __builtin_amdgcn_mfma_f32_16x16x32_bf16(ah[m], bl[n], acc[m][n], 0, 0, 0);
        acc[m][n] = __builtin_amdgcn_mfma_f32_16x16x32_bf16(al[m], bh[n], acc[m][n], 0, 0, 0);
      }
  }
#undef STAGE

  float* Cb = C + (size_t)bz * sCb;
  const size_t m0 = (size_t)bx * 128, n0 = (size_t)by * 128;
#pragma unroll
  for (int n = 0; n < 4; ++n) {
    const size_t col = n0 + wc + n * 16 + lr;
    const float bval = bias ? bias[(size_t)bz * sBiasB + col] : 0.0f;
#pragma unroll
    for (int m = 0; m < 4; ++m) {
      const size_t rb = m0 + wr + m * 16 + ksl * 4;
#pragma unroll
      for (int r = 0; r < 4; ++r)
        Cb[(rb + r) * 1024 + col] = acc[m][n][r] + bval;
    }
  }
}

// ---------------------------------------------------------------------------
// bias-correction inputs: column sums of key/value, u = Wk^T ksum, w = Wv^T vsum
// ---------------------------------------------------------------------------
__global__ __launch_bounds__(256) void colsum2(const float* __restrict__ key,
                                               const float* __restrict__ value,
                                               float* __restrict__ kvpart) {
  const int dseg = blockIdx.x, sc = blockIdx.y, b = blockIdx.z;  // (4,8,4)
  const int d = dseg * 256 + threadIdx.x;
  const float* kp = key + (size_t)b * 2097152 + (size_t)sc * 256 * 1024 + d;
  const float* vp = value + (size_t)b * 2097152 + (size_t)sc * 256 * 1024 + d;
  float sk = 0.f, sv = 0.f;
  for (int s = 0; s < 256; ++s) {
    sk += kp[(size_t)s * 1024];
    sv += vp[(size_t)s * 1024];
  }
  kvpart[((size_t)b * 8 + sc) * 1024 + d] = sk;
  kvpart[32768 + ((size_t)b * 8 + sc) * 1024 + d] = sv;
}

__global__ __launch_bounds__(256) void reduceks(const float* __restrict__ kvpart,
                                                float* __restrict__ ksum,
                                                float* __restrict__ vsum) {
  const int idx = blockIdx.x * 256 + threadIdx.x;  // 4096
  const int b = idx >> 10, d = idx & 1023;
  float sk = 0.f, sv = 0.f;
#pragma unroll
  for (int sc = 0; sc < 8; ++sc) {
    sk += kvpart[((size_t)b * 8 + sc) * 1024 + d];
    sv += kvpart[32768 + ((size_t)b * 8 + sc) * 1024 + d];
  }
  ksum[idx] = sk;
  vsum[idx] = sv;
}

__global__ __launch_bounds__(256) void uvpart_kernel(
    const float* __restrict__ Wk, const float* __restrict__ Wv,
    const float* __restrict__ ksum, const float* __restrict__ vsum,
    float* __restrict__ part) {
  const int iseg = blockIdx.x;                          // 4
  const int dc = blockIdx.y & 7, kv = blockIdx.y >> 3;  // y: 16
  const int b = blockIdx.z;
  const int i = iseg * 256 + threadIdx.x;
  const float* W = kv ? Wv : Wk;
  const float* sv = (kv ? vsum : ksum) + b * 1024 + dc * 128;
  float s = 0.f;
  for (int dd = 0; dd < 128; ++dd)
    s += W[(size_t)(dc * 128 + dd) * 1024 + i] * sv[dd];
  part[(((size_t)kv * 4 + b) * 8 + dc) * 1024 + i] = s;
}

__global__ __launch_bounds__(256) void reduceuv(const float* __restrict__ part,
                                                float* __restrict__ uv) {
  const int idx = blockIdx.x * 256 + threadIdx.x;  // 8192
  const int kb = idx >> 10, i = idx & 1023;
  float s = 0.f;
#pragma unroll
  for (int dc = 0; dc < 8; ++dc) s += part[((size_t)kb * 8 + dc) * 1024 + i];
  uv[idx] = s;
}

// ---------------------------------------------------------------------------
// mstep: Mpart[chunk][bh][r][c] = sum_{e in chunk(256)} T[b][h64+r][e]*Wv[e][h64+c]
// ---------------------------------------------------------------------------
__global__ __launch_bounds__(256) void mstep(const float* __restrict__ T,
                                             const float* __restrict__ Wv,
                                             float* __restrict__ Mpart) {
  const int chunk = blockIdx.x;  // 0..3
  const int bh = blockIdx.y;
  const int b = bh >> 4, h = bh & 15;
  __shared__ float Ts[64][68];
  __shared__ float Ws[64][68];
  const int tid = threadIdx.x;
  const int r0 = tid >> 4, c0 = (tid & 15) * 4;
  float acc[4][4] = {};
  const int e0 = chunk * 256;
  for (int slab = 0; slab < 4; ++slab) {
    __syncthreads();
#pragma unroll
    for (int t = 0; t < 4; ++t) {
      const int task = tid + t * 256;
      const int si = task >> 4, c4 = (task & 15) * 4;
      *(float4*)&Ts[si][c4] = *(const float4*)&T[(size_t)b * 1048576 +
                                                 (size_t)(h * 64 + si) * 1024 +
                                                 e0 + slab * 64 + c4];
      *(float4*)&Ws[si][c4] =
          *(const float4*)&Wv[(size_t)(e0 + slab * 64 + si) * 1024 + h * 64 + c4];
    }
    __syncthreads();
    for (int e = 0; e < 64; ++e) {
      const float4 wv = *(const float4*)&Ws[e][c0];
#pragma unroll
      for (int i = 0; i < 4; ++i) {
        const float tt = Ts[r0 + 16 * i][e];
        acc[i][0] += tt * wv.x;
        acc[i][1] += tt * wv.y;
        acc[i][2] += tt * wv.z;
        acc[i][3] += tt * wv.w;
      }
    }
  }
  float* outp = Mpart + ((size_t)chunk * 64 + bh) * 4096;
#pragma unroll
  for (int i = 0; i < 4; ++i)
    *(float4*)&outp[(r0 + 16 * i) * 64 + c0] = *(float4*)&acc[i][0];
}

// M = sum(Mpart) + rank-1 bias corrections
__global__ __launch_bounds__(256) void reduce4corr(
    const float* __restrict__ Mpart, const float* __restrict__ uv,
    const float* __restrict__ bk, const float* __restrict__ bv,
    float* __restrict__ M) {
  const int idx = blockIdx.x * 256 + threadIdx.x;  // 262144
  const int bh = idx >> 12, b = bh >> 4, h = bh & 15;
  const int rc = idx & 4095;
  const int r = h * 64 + (rc >> 6), c = h * 64 + (rc & 63);
  float s = Mpart[idx] + Mpart[262144 + idx] + Mpart[524288 + idx] +
            Mpart[786432 + idx];
  s += uv[b * 1024 + r] * bv[c] + bk[r] * uv[4096 + b * 1024 + c] +
       2048.0f * bk[r] * bv[c];
  M[idx] = s;
}

// ---------------------------------------------------------------------------
// WqM[b][d][h*64+c] = 0.125 * sum_r Wq[d][h*64+r] * M[b,h][r][c]
// ---------------------------------------------------------------------------
__global__ __launch_bounds__(256) void wqm_kernel(const float* __restrict__ M,
                                                  const float* __restrict__ Wq,
                                                  float* __restrict__ WqM) {
  const int dseg = blockIdx.x, h = blockIdx.y, b = blockIdx.z;
  __shared__ __align__(16) float WqS[128][68];
  __shared__ __align__(16) float Ms[64][68];
  const int t = threadIdx.x;
#pragma unroll
  for (int it = 0; it < 8; ++it) {
    const int task = t + it * 256;
    const int row = task >> 4, c4 = (task & 15) * 4;
    *(float4*)&WqS[row][c4] =
        *(const float4*)&Wq[(size_t)(dseg * 128 + row) * 1024 + h * 64 + c4];
  }
#pragma unroll
  for (int it = 0; it < 4; ++it) {
    const int task = t + it * 256;
    const int row = task >> 4, c4 = (task & 15) * 4;
    *(float4*)&Ms[row][c4] =
        *(const float4*)&M[((size_t)(b * 16 + h)) * 4096 + row * 64 + c4];
  }
  __syncthreads();

  const int c0 = (t & 7) * 8;
  const int d0 = t >> 3;
  float4 a0[4], a1[4];
#pragma unroll
  for (int i = 0; i < 4; ++i) {
    a0[i] = float4{0.f, 0.f, 0.f, 0.f};
    a1[i] = float4{0.f, 0.f, 0.f, 0.f};
  }
  for (int r = 0; r < 64; ++r) {
    const float4 m0 = *(const float4*)&Ms[r][c0];
    const float4 m1 = *(const float4*)&Ms[r][c0 + 4];
#pragma unroll
    for (int i = 0; i < 4; ++i) {
      const float w = WqS[d0 + 32 * i][r];
      a0[i].x += w * m0.x; a0[i].y += w * m0.y; a0[i].z += w * m0.z; a0[i].w += w * m0.w;
      a1[i].x += w * m1.x; a1[i].y += w * m1.y; a1[i].z += w * m1.z; a1[i].w += w * m1.w;
    }
  }
#pragma unroll
  for (int i = 0; i < 4; ++i) {
    const size_t row = (size_t)(dseg * 128 + d0 + 32 * i);
    float* p = WqM + ((size_t)b << 20) + row * 1024 + h * 64 + c0;
    float4 o0 = a0[i], o1 = a1[i];
    o0.x *= 0.125f; o0.y *= 0.125f; o0.z *= 0.125f; o0.w *= 0.125f;
    o1.x *= 0.125f; o1.y *= 0.125f; o1.z *= 0.125f; o1.w *= 0.125f;
    *(float4*)p = o0;
    *(float4*)(p + 4) = o1;
  }
}

// bqM[b][h*64+c] = sum_r bq[h*64+r] * M[b,h][r][c]
__global__ __launch_bounds__(256) void bqm_kernel(const float* __restrict__ M,
                                                  const float* __restrict__ bq,
                                                  float* __restrict__ bqM) {
  const int h = blockIdx.x, b = blockIdx.y;
  __shared__ float part[4][64];
  const int t = threadIdx.x;
  const int c = t & 63, rq = t >> 6;
  const float* Mb = M + ((size_t)(b * 16 + h)) * 4096;
  float s = 0.f;
#pragma unroll
  for (int ri = 0; ri < 16; ++ri) {
    const int r = rq * 16 + ri;
    s += bq[h * 64 + r] * Mb[r * 64 + c];
  }
  part[rq][c] = s;
  __syncthreads();
  if (t < 64) {
    bqM[(size_t)b * 1024 + h * 64 + t] =
        part[0][t] + part[1][t] + part[2][t] + part[3][t];
  }
}

// cv[b][j] = bo[j] + 0.125 * sum_k bqM[b][k] * Wo[k][j]
__global__ __launch_bounds__(256) void cv_kernel(const float* __restrict__ bqM,
                                                 const float* __restrict__ Wo,
                                                 const float* __restrict__ bo,
                                                 float* __restrict__ cv) {
  const int j = blockIdx.x * 256 + threadIdx.x;
  const int b = blockIdx.y;
  const float* q = bqM + (size_t)b * 1024;
  float s = 0.f;
  for (int k = 0; k < 1024; ++k) s += q[k] * Wo[(size_t)k * 1024 + j];
  cv[(size_t)b * 1024 + j] = s * 0.125f + bo[j];
}

extern "C" void kernel_launch(void* const* d_in, const int* in_sizes, int n_in,
                              void* d_out, int out_size, void* d_ws,
                              size_t ws_size, hipStream_t stream) {
  const float* query = (const float*)d_in[0];
  const float* key = (const float*)d_in[1];
  const float* value = (const float*)d_in[2];
  const float* Wq = (const float*)d_in[3];
  const float* bq = (const float*)d_in[4];
  const float* Wk = (const float*)d_in[5];
  const float* bk = (const float*)d_in[6];
  const float* Wv = (const float*)d_in[7];
  const float* bv = (const float*)d_in[8];
  const float* Wo = (const float*)d_in[9];
  const float* bo = (const float*)d_in[10];
  float* out = (float*)d_out;
  float* ws = (float*)d_ws;

  // ---- workspace layout (float offsets; regions reused after producers die)
  unsigned short* KTimg = (unsigned short*)(ws);             // [0, 8388608)
  unsigned short* VTimg = (unsigned short*)(ws + 8388608);   // [8388608, 16777216)
  float* D = ws + 16777216;                                  // [16777216, 20971520)
  unsigned short* Dimg = (unsigned short*)(ws);              // [0, 4194304)  (KTimg dead)
  unsigned short* WkTimg = (unsigned short*)(ws + 4194304);  // [4194304, 5242880)
  unsigned short* WoTimg = (unsigned short*)(ws + 5242880);  // [5242880, 6291456)
  float* T = ws + 6291456;                                   // [6291456, 10485760)
  float* Mpart = ws + 10485760;                              // [10485760, 11534336)
  float* Msum = ws + 11534336;                               // [11534336, 11796480)
  float* WqM = ws + 11804672;                                // [11804672, 15998976)
  unsigned short* WqMimg = (unsigned short*)(ws + 16777216); // reuse D region
  float* FT = ws;                                            // [0, 4194304) (Dimg dead)
  unsigned short* FTimg = (unsigned short*)(ws + 6291456);   // reuse T region
  unsigned short* Qimg = (unsigned short*)(ws + 10485760);   // [10485760, 18874368)
  float* cv = ws + 20971520;
  float* bqM = ws + 20975616;
  float* ksum = ws + 20979712;
  float* vsum = ws + 20983808;
  float* uv = ws + 20987904;
  float* kvpart = ws + 20996096;  // 65536, reused as uvpart

  // ---- phase 1: images of key^T / value^T; bias-correction sums
  tileimg<<<dim3(8, 64, 4), 256, 0, stream>>>(key, 2097152, 1, KTimg);
  tileimg<<<dim3(8, 64, 4), 256, 0, stream>>>(value, 2097152, 1, VTimg);
  colsum2<<<dim3(4, 8, 4), 256, 0, stream>>>(key, value, kvpart);
  reduceks<<<16, 256, 0, stream>>>(kvpart, ksum, vsum);
  uvpart_kernel<<<dim3(4, 16, 4), 256, 0, stream>>>(Wk, Wv, ksum, vsum, kvpart);
  reduceuv<<<32, 256, 0, stream>>>(kvpart, uv);

  // ---- D[b] = value^T key  (= C^T), K=2048
  gemm_img<<<dim3(8, 8, 4), 256, 0, stream>>>(VTimg, 4194304, KTimg, 4194304,
                                              (const float*)nullptr, 0, D,
                                              1048576, 64);

  // ---- T[b] = WkT . D^T  (= Wk^T C)
  tileimg<<<dim3(8, 32, 4), 256, 0, stream>>>(D, 1048576, 0, Dimg);
  tileimg<<<dim3(8, 32, 1), 256, 0, stream>>>(Wk, 0, 1, WkTimg);
  tileimg<<<dim3(8, 32, 1), 256, 0, stream>>>(Wo, 0, 1, WoTimg);
  gemm_img<<<dim3(8, 8, 4), 256, 0, stream>>>(WkTimg, 0, Dimg, 2097152,
                                              (const float*)nullptr, 0, T,
                                              1048576, 32);

  // ---- M[b,h] = T_h . Wv_h + rank-1 bias corrections (fp32 exact)
  mstep<<<dim3(4, 64), 256, 0, stream>>>(T, Wv, Mpart);
  reduce4corr<<<1024, 256, 0, stream>>>(Mpart, uv, bk, bv, Msum);

  // ---- WqM, cv
  wqm_kernel<<<dim3(8, 16, 4), 256, 0, stream>>>(Msum, Wq, WqM);
  bqm_kernel<<<dim3(16, 4), 256, 0, stream>>>(Msum, bq, bqM);
  cv_kernel<<<dim3(4, 4), 256, 0, stream>>>(bqM, Wo, bo, cv);

  // ---- FT[b] = (WqM[b] @ Wo)^T = gemm(A=WoT, BT=WqM)
  tileimg<<<dim3(8, 32, 4), 256, 0, stream>>>(WqM, 1048576, 0, WqMimg);
  gemm_img<<<dim3(8, 8, 4), 256, 0, stream>>>(WoTimg, 0, WqMimg, 2097152,
                                              (const float*)nullptr, 0, FT,
                                              1048576, 32);

  // ---- out[b] = query[b] @ FT[b]^T + cv[b]
  tileimg<<<dim3(8, 32, 4), 256, 0, stream>>>(FT, 1048576, 0, FTimg);
  tileimg<<<dim3(16, 32, 4), 256, 0, stream>>>(query, 2097152, 0, Qimg);
  gemm_img<<<dim3(16, 8, 4), 256, 0, stream>>>(Qimg, 4194304, FTimg, 2097152,
                                               cv, 1024, out, 2097152, 32);
}